// Round 5
// baseline (299.009 us; speedup 1.0000x reference)
//
#include <hip/hip_runtime.h>

#define IMG_H 224
#define IMG_W 224
#define HW (IMG_H * IMG_W)
#define NUM_ROWS 159
#define NUM_COLS 1024
#define BATCH 128
#define OVF_CAP 4096

// Exact integer sqrt (v <= ~25k here, f32 sqrt + fixup loops).
__device__ __forceinline__ int isqrt_i(int v) {
    int u = (int)sqrtf((float)v);
    while (u > 0 && u * u > v) --u;
    while ((u + 1) * (u + 1) <= v) ++u;
    return u;
}

// ---------------------------------------------------------------------------
// Analytic ring build (verified R3/R4). round(sqrt(dx^2+dy^2)) == d
//   <=>  Araw <= dx^2+dy^2 <= d^2+d,  Araw = (d==0 ? 0 : d^2-d+1)
// ---------------------------------------------------------------------------
__global__ __launch_bounds__(256) void build_rings(int* __restrict__ ring_pix,
                                                   int* __restrict__ ring_cnt,
                                                   int* __restrict__ ovf_cnt) {
    const int d = blockIdx.x;
    const int tid = threadIdx.x;  // y = tid for tid < 224
    __shared__ int scnt[256];
    if (d == 0 && tid == 0) ovf_cnt[0] = 0;

    int cnt = 0;
    int x0l = 0, x1l = -1, x0r = 0, x1r = -1;
    if (tid < IMG_H) {
        const int dy = tid - 112;
        const int Araw = (d == 0) ? 0 : (d * d - d + 1);
        int A = Araw - dy * dy;
        if (A < 0) A = 0;
        const int B = d * d + d - dy * dy;
        if (B >= 0) {
            const int hi = isqrt_i(B);
            int lo = isqrt_i(A);
            if (lo * lo < A) ++lo;
            if (lo <= hi) {
                if (lo == 0) {
                    x0l = 112 - min(hi, 112);
                    x1l = 112 + min(hi, 111);
                } else {
                    x0l = 112 - min(hi, 112);
                    x1l = 112 - lo;
                    x0r = 112 + lo;
                    x1r = 112 + min(hi, 111);
                }
                cnt = max(0, x1l - x0l + 1) + max(0, x1r - x0r + 1);
            }
        }
    }
    scnt[tid] = cnt;
    __syncthreads();
    for (int off = 1; off < 256; off <<= 1) {
        const int mine = scnt[tid];
        const int add = (tid >= off) ? scnt[tid - off] : 0;
        __syncthreads();
        scnt[tid] = mine + add;
        __syncthreads();
    }
    if (tid < IMG_H && cnt > 0) {
        int j = d * NUM_COLS + (scnt[tid] - cnt);
        const int rowbase = tid * IMG_W;
        for (int x = x0l; x <= x1l; ++x) ring_pix[j++] = rowbase + x;
        for (int x = x0r; x <= x1r; ++x) ring_pix[j++] = rowbase + x;
    }
    if (tid == 255) ring_cnt[d] = scnt[255];
}

// ---------------------------------------------------------------------------
// Per-wave gather + stable compaction (verified R4). Key =
// prand_bits(30b) << 16 | pixel(16b): unique, and sorting by it == stable
// (prand, col) order. Writes pass-through pixels directly. Returns k.
// ---------------------------------------------------------------------------
__device__ __forceinline__ int gather_ring(
    int b, int d, int lane, int cap,
    const float* __restrict__ img, const float* __restrict__ mask,
    const float* __restrict__ prand, float* __restrict__ out,
    const int* __restrict__ ring_pix, int n,
    unsigned long long* __restrict__ wskey) {
    const float* imgb  = img  + (size_t)b * HW;
    const float* maskb = mask + (size_t)b * HW;
    const float* prb   = prand + ((size_t)b * NUM_ROWS + d) * NUM_COLS;
    float* outb = out + (size_t)b * HW;
    const unsigned long long ltmask = (1ull << lane) - 1ull;
    int base = 0;
    for (int c = 0; c < n; c += 64) {
        const int i = c + lane;
        bool sel = false;
        int p = 0;
        unsigned kb = 0;
        if (i < n) {
            p = ring_pix[d * NUM_COLS + i];
            const float v = imgb[p];
            kb = __float_as_uint(prb[i]);  // prand in [0,1): bits order-preserving
            sel = (maskb[p] < 0.5f);
            if (!sel) outb[p] = v;         // pass-through
        }
        const unsigned long long ball = __ballot(sel);
        if (sel) {
            const int j = base + __popcll(ball & ltmask);
            if (j < cap) wskey[j] = ((unsigned long long)kb << 16) | (unsigned)p;
        }
        base += __popcll(ball);
    }
    return base;
}

// ---------------------------------------------------------------------------
// Rank-by-counting permutation (no sort, no dependent stage chain):
//   rank(i) = #{ j : key_j < key_i }   (keys unique -> exact stable order)
// Element i's value must land at pix[rank(i)]; equivalently (inverted via
// sinv) pix[i] receives the value of element sinv[i]. Stores are issued in
// ascending compact order i -> coalesced along the ring arc.
// Caller pads skey[k..kp) with ~0 sentinels (kp = roundup64(k)); sentinel
// keys are > all real keys so they contribute 0 to every count.
// ---------------------------------------------------------------------------
template <int E2>
__device__ void rank_scatter(const unsigned long long* __restrict__ wskey,
                             unsigned short* __restrict__ winv,
                             int k, int kp, int lane,
                             const float* __restrict__ imgb,
                             float* __restrict__ outb) {
    unsigned long long ki[E2];
    int cnt[E2];
#pragma unroll
    for (int e = 0; e < E2; ++e) {
        const int i = lane + 64 * e;
        ki[e] = (i < k) ? wskey[i] : ~0ull;
        cnt[e] = 0;
    }
    // Independent compare+count: wave-uniform broadcast reads of skey[j],
    // no cross-iteration dependency -> fully pipelined.
#pragma unroll 4
    for (int j = 0; j < kp; ++j) {
        const unsigned long long kj = wskey[j];
#pragma unroll
        for (int e = 0; e < E2; ++e) cnt[e] += (kj < ki[e]) ? 1 : 0;
    }
#pragma unroll
    for (int e = 0; e < E2; ++e) {
        const int i = lane + 64 * e;
        if (i < k) winv[cnt[e]] = (unsigned short)i;
    }
    __syncthreads();
#pragma unroll
    for (int e = 0; e < E2; ++e) {
        const int i = lane + 64 * e;
        if (i < k) {
            const int src = winv[i];                        // element with rank i
            const int srcpix = (int)(wskey[src] & 0xFFFFull);
            const int dstpix = (int)(ki[e] & 0xFFFFull);    // own pixel
            outb[dstpix] = imgb[srcpix];                    // img L1/L2-hot
        }
    }
}

__device__ __forceinline__ void rank_dispatch(
    const unsigned long long* wskey, unsigned short* winv, int k, int lane,
    const float* imgb, float* outb) {
    const int kp = (k + 63) & ~63;
    if (k <= 64)       rank_scatter<1>(wskey, winv, k, kp, lane, imgb, outb);
    else if (k <= 128) rank_scatter<2>(wskey, winv, k, kp, lane, imgb, outb);
    else if (k <= 192) rank_scatter<3>(wskey, winv, k, kp, lane, imgb, outb);
    else if (k <= 256) rank_scatter<4>(wskey, winv, k, kp, lane, imgb, outb);
    else               rank_scatter<8>(wskey, winv, k, kp, lane, imgb, outb);
}

// ---------------------------------------------------------------------------
// Main: one WAVE per (batch, ring); 4 waves/block; XCD-swizzled (16 whole
// images per XCD). LDS: 4 x (512 u64 keys + 512 u16 inv) = 20 KB -> 8
// blocks/CU possible.
// ---------------------------------------------------------------------------
__global__ __launch_bounds__(256) void radial_shuffle(
    const float* __restrict__ img, const float* __restrict__ mask,
    const float* __restrict__ prand, float* __restrict__ out,
    const int* __restrict__ ring_pix, const int* __restrict__ ring_cnt,
    int* __restrict__ ovf_cnt, int* __restrict__ ovf_list) {
    const int tid = threadIdx.x;
    const int wid = tid >> 6;
    const int lane = tid & 63;
    const int xcd = blockIdx.x & 7;
    const int g = (blockIdx.x >> 3) * 4 + wid;  // 0..2543 within XCD
    const int b = xcd * (BATCH / 8) + g / NUM_ROWS;
    const int d = g % NUM_ROWS;
    const int n = ring_cnt[d];

    __shared__ unsigned long long skey_s[4][512];  // 16 KB
    __shared__ unsigned short sinv_s[4][512];      // 4 KB
    unsigned long long* wskey = skey_s[wid];
    unsigned short* winv = sinv_s[wid];

    const int k = gather_ring(b, d, lane, 512, img, mask, prand, out,
                              ring_pix, n, wskey);
    // sentinel-pad to multiple of 64 so the rank j-loop needs no guards
    if (k <= 512) {
        const int kp = (k + 63) & ~63;
        for (int j = k + lane; j < kp; j += 64) wskey[j] = ~0ull;
    }
    __syncthreads();

    if (k > 512) {
        // ~+12 sigma binomial tail: defer to overflow kernel
        if (lane == 0) {
            const int idx = atomicAdd(ovf_cnt, 1);
            if (idx < OVF_CAP) ovf_list[idx] = b * NUM_ROWS + d;
        }
    } else if (k > 0) {
        rank_dispatch(wskey, winv, k, lane,
                      img + (size_t)b * HW, out + (size_t)b * HW);
    }
}

// Cold path: rings with k > 512 (capacity 768 >= max ring ~703).
__global__ __launch_bounds__(64) void overflow_sort(
    const float* __restrict__ img, const float* __restrict__ mask,
    const float* __restrict__ prand, float* __restrict__ out,
    const int* __restrict__ ring_pix, const int* __restrict__ ring_cnt,
    const int* __restrict__ ovf_cnt, const int* __restrict__ ovf_list) {
    __shared__ unsigned long long wskey[768];
    __shared__ unsigned short winv[768];
    const int m = min(*ovf_cnt, OVF_CAP);
    const int lane = threadIdx.x;
    for (int t = blockIdx.x; t < m; t += gridDim.x) {
        const int bd = ovf_list[t];
        const int b = bd / NUM_ROWS;
        const int d = bd % NUM_ROWS;
        const int k = gather_ring(b, d, lane, 768, img, mask, prand, out,
                                  ring_pix, ring_cnt[d], wskey);
        const int kp = (k + 63) & ~63;
        for (int j = k + lane; j < kp; j += 64) wskey[j] = ~0ull;
        __syncthreads();
        rank_scatter<12>(wskey, winv, k, kp, lane,
                         img + (size_t)b * HW, out + (size_t)b * HW);
        __syncthreads();  // before wskey reuse
    }
}

extern "C" void kernel_launch(void* const* d_in, const int* in_sizes, int n_in,
                              void* d_out, int out_size, void* d_ws, size_t ws_size,
                              hipStream_t stream) {
    const float* img   = (const float*)d_in[0];  // (128,224,224,1) f32
    const float* mask  = (const float*)d_in[1];  // (128,224,224)   f32
    const float* prand = (const float*)d_in[2];  // (128,159,1024)  f32
    float* out = (float*)d_out;                  // (128,224,224,1) f32

    int* ring_pix = (int*)d_ws;                       // 159*1024 ints
    int* ring_cnt = ring_pix + NUM_ROWS * NUM_COLS;   // 159 ints
    int* ovf_cnt  = ring_cnt + NUM_ROWS;              // 1 int
    int* ovf_list = ovf_cnt + 1;                      // OVF_CAP ints

    hipLaunchKernelGGL(build_rings, dim3(NUM_ROWS), dim3(256), 0, stream,
                       ring_pix, ring_cnt, ovf_cnt);
    hipLaunchKernelGGL(radial_shuffle, dim3(BATCH * NUM_ROWS / 4), dim3(256), 0,
                       stream, img, mask, prand, out, ring_pix, ring_cnt,
                       ovf_cnt, ovf_list);
    hipLaunchKernelGGL(overflow_sort, dim3(32), dim3(64), 0, stream,
                       img, mask, prand, out, ring_pix, ring_cnt,
                       ovf_cnt, ovf_list);
}

// Round 7
// 249.922 us; speedup vs baseline: 1.1964x; 1.1964x over previous
//
#include <hip/hip_runtime.h>

#define IMG_H 224
#define IMG_W 224
#define HW (IMG_H * IMG_W)
#define NUM_ROWS 159
#define NUM_COLS 1024
#define BATCH 128
#define OVF_CAP 4096
#define MAXC 12  // static prefetch covers 768; dynamic tail handles any excess

// Exact integer sqrt (v <= ~25k here, f32 sqrt + fixup loops).
__device__ __forceinline__ int isqrt_i(int v) {
    int u = (int)sqrtf((float)v);
    while (u > 0 && u * u > v) --u;
    while ((u + 1) * (u + 1) <= v) ++u;
    return u;
}

// ---------------------------------------------------------------------------
// Analytic ring build (verified R3-R5). round(sqrt(dx^2+dy^2)) == d
//   <=>  Araw <= dx^2+dy^2 <= d^2+d,  Araw = (d==0 ? 0 : d^2-d+1)
// ---------------------------------------------------------------------------
__global__ __launch_bounds__(256) void build_rings(int* __restrict__ ring_pix,
                                                   int* __restrict__ ring_cnt,
                                                   int* __restrict__ ovf_cnt) {
    const int d = blockIdx.x;
    const int tid = threadIdx.x;  // y = tid for tid < 224
    __shared__ int scnt[256];
    if (d == 0 && tid == 0) ovf_cnt[0] = 0;

    int cnt = 0;
    int x0l = 0, x1l = -1, x0r = 0, x1r = -1;
    if (tid < IMG_H) {
        const int dy = tid - 112;
        const int Araw = (d == 0) ? 0 : (d * d - d + 1);
        int A = Araw - dy * dy;
        if (A < 0) A = 0;
        const int B = d * d + d - dy * dy;
        if (B >= 0) {
            const int hi = isqrt_i(B);
            int lo = isqrt_i(A);
            if (lo * lo < A) ++lo;
            if (lo <= hi) {
                if (lo == 0) {
                    x0l = 112 - min(hi, 112);
                    x1l = 112 + min(hi, 111);
                } else {
                    x0l = 112 - min(hi, 112);
                    x1l = 112 - lo;
                    x0r = 112 + lo;
                    x1r = 112 + min(hi, 111);
                }
                cnt = max(0, x1l - x0l + 1) + max(0, x1r - x0r + 1);
            }
        }
    }
    scnt[tid] = cnt;
    __syncthreads();
    for (int off = 1; off < 256; off <<= 1) {
        const int mine = scnt[tid];
        const int add = (tid >= off) ? scnt[tid - off] : 0;
        __syncthreads();
        scnt[tid] = mine + add;
        __syncthreads();
    }
    if (tid < IMG_H && cnt > 0) {
        int j = d * NUM_COLS + (scnt[tid] - cnt);
        const int rowbase = tid * IMG_W;
        for (int x = x0l; x <= x1l; ++x) ring_pix[j++] = rowbase + x;
        for (int x = x0r; x <= x1r; ++x) ring_pix[j++] = rowbase + x;
    }
    if (tid == 255) ring_cnt[d] = scnt[255];
}

// ---------------------------------------------------------------------------
// Software-pipelined gather: phase 1 loads all ring_pix chunks (independent);
// phase 2 issues ALL img/mask/prand loads back-to-back; phase 3 ballot/
// compact. A dynamic tail covers n > 64*MAXC (R6 lesson: never bound ring
// size at compile time — a ring with n > 704 silently corrupted every rank).
// Key = prand_bits(30b) << 16 | pixel(16b): unique; sorting by it == stable
// (prand, col) order (verified R4). Returns k (#selected).
// ---------------------------------------------------------------------------
__device__ __forceinline__ int gather_ring(
    int b, int d, int lane, int cap,
    const float* __restrict__ img, const float* __restrict__ mask,
    const float* __restrict__ prand, float* __restrict__ out,
    const int* __restrict__ ring_pix, int n,
    unsigned long long* __restrict__ wskey) {
    const float* imgb  = img  + (size_t)b * HW;
    const float* maskb = mask + (size_t)b * HW;
    const float* prb   = prand + ((size_t)b * NUM_ROWS + d) * NUM_COLS;
    float* outb = out + (size_t)b * HW;
    const unsigned long long ltmask = (1ull << lane) - 1ull;
    const int* rp = ring_pix + d * NUM_COLS;

    int p[MAXC];
    float v[MAXC], m[MAXC];
    unsigned kb[MAXC];
#pragma unroll
    for (int c = 0; c < MAXC; ++c) {
        const int i = c * 64 + lane;
        p[c] = rp[min(i, n - 1)];  // clamped: always valid, dup loads coalesce
    }
#pragma unroll
    for (int c = 0; c < MAXC; ++c) v[c] = imgb[p[c]];
#pragma unroll
    for (int c = 0; c < MAXC; ++c) m[c] = maskb[p[c]];
#pragma unroll
    for (int c = 0; c < MAXC; ++c) kb[c] = __float_as_uint(prb[min(c * 64 + lane, NUM_COLS - 1)]);

    int base = 0;
#pragma unroll
    for (int c = 0; c < MAXC; ++c) {
        const int i = c * 64 + lane;
        const bool active = (i < n);
        const bool sel = active && (m[c] < 0.5f);
        if (active && !sel) outb[p[c]] = v[c];  // pass-through
        const unsigned long long ball = __ballot(sel);
        if (sel) {
            const int j = base + __popcll(ball & ltmask);
            if (j < cap) wskey[j] = ((unsigned long long)kb[c] << 16) | (unsigned)p[c];
        }
        base += __popcll(ball);
    }
    // Dynamic tail (defensive; taken only if some ring has n > 64*MAXC).
    for (int c0 = MAXC * 64; c0 < n; c0 += 64) {
        const int i = c0 + lane;
        bool sel = false;
        int pp = 0;
        unsigned kk = 0;
        if (i < n) {
            pp = rp[i];
            const float vv = imgb[pp];
            kk = __float_as_uint(prb[min(i, NUM_COLS - 1)]);
            sel = (maskb[pp] < 0.5f);
            if (!sel) outb[pp] = vv;
        }
        const unsigned long long ball = __ballot(sel);
        if (sel) {
            const int j = base + __popcll(ball & ltmask);
            if (j < cap) wskey[j] = ((unsigned long long)kk << 16) | (unsigned)pp;
        }
        base += __popcll(ball);
    }
    return base;
}

// ---------------------------------------------------------------------------
// Wave-level register bitonic sort of P = 64*E keys (blocked layout, pos =
// lane*E + e). Cross-lane strides via __shfl_xor; strides < E in-register.
// (Verified R4.)
// ---------------------------------------------------------------------------
template <int LOGE>
__device__ __forceinline__ void sort_keys(unsigned long long* key, int lane) {
    constexpr int E = 1 << LOGE;
    const int P = 64 << LOGE;
    const int base = lane << LOGE;
    for (int size = 2; size <= P; size <<= 1) {
        const bool upw = ((base & size) == 0);
        for (int stride = size >> 1; stride >= E; stride >>= 1) {
            const int lx = stride >> LOGE;
            const bool keepmin = (((lane & lx) == 0) == upw);
#pragma unroll
            for (int e = 0; e < E; ++e) {
                const unsigned long long mine = key[e];
                const unsigned long long other = __shfl_xor(mine, lx, 64);
                const unsigned long long lo = mine < other ? mine : other;
                const unsigned long long hi = mine < other ? other : mine;
                key[e] = keepmin ? lo : hi;
            }
        }
#pragma unroll
        for (int sbit = LOGE - 1; sbit >= 0; --sbit) {
            const int s = 1 << sbit;
            if (s < size) {
#pragma unroll
                for (int e = 0; e < E; ++e) {
                    if ((e & s) == 0) {
                        const int f = e | s;
                        const bool up = (((base | e) & size) == 0);
                        const unsigned long long a = key[e];
                        const unsigned long long b = key[f];
                        const unsigned long long lo = a < b ? a : b;
                        const unsigned long long hi = a < b ? b : a;
                        key[e] = up ? lo : hi;
                        key[f] = up ? hi : lo;
                    }
                }
            }
        }
    }
}

// Hot epilogue: restage src pixels by rank through LDS (u16), then issue the
// img gather + out scatter in compact-slot (arc-contiguous) order — restores
// coalescing. Wave-private LDS: explicit lgkmcnt(0) instead of block barrier.
template <int LOGE>
__device__ void sort_scatter(unsigned long long* __restrict__ wskey,
                             unsigned short* __restrict__ wsrc,
                             int k, int lane,
                             const float* __restrict__ imgb,
                             float* __restrict__ outb) {
    constexpr int E = 1 << LOGE;
    const int base = lane << LOGE;
    unsigned long long key[E];
#pragma unroll
    for (int e = 0; e < E; ++e) {
        const int j = base + e;
        key[e] = (j < k) ? wskey[j] : ~0ull;
    }
    sort_keys<LOGE>(key, lane);
#pragma unroll
    for (int e = 0; e < E; ++e) {
        const int r = base + e;
        if (r < k) wsrc[r] = (unsigned short)key[e];  // src pixel of rank r
    }
    asm volatile("s_waitcnt lgkmcnt(0)" ::: "memory");
    const unsigned* wk32 = (const unsigned*)wskey;  // low word of key j
#pragma unroll
    for (int e = 0; e < E; ++e) {
        const int j = lane + 64 * e;  // cyclic: consecutive lanes = consecutive slots
        if (j < k) {
            const int psrc = wsrc[j];
            const int pdst = (int)(wk32[2 * j] & 0xFFFFu);  // pre-sort slot pixel
            outb[pdst] = imgb[psrc];
        }
    }
}

// ---------------------------------------------------------------------------
// Main: one WAVE per (batch, ring); 4 waves/block; XCD-swizzled (16 whole
// images per XCD). No block barriers — waves fully independent.
// LDS: 4 x (512 u64 + 512 u16) = 20 KB.
// ---------------------------------------------------------------------------
__global__ __launch_bounds__(256) void radial_shuffle(
    const float* __restrict__ img, const float* __restrict__ mask,
    const float* __restrict__ prand, float* __restrict__ out,
    const int* __restrict__ ring_pix, const int* __restrict__ ring_cnt,
    int* __restrict__ ovf_cnt, int* __restrict__ ovf_list) {
    const int tid = threadIdx.x;
    const int wid = tid >> 6;
    const int lane = tid & 63;
    const int xcd = blockIdx.x & 7;
    const int g = (blockIdx.x >> 3) * 4 + wid;  // 0..2543 within XCD
    const int b = xcd * (BATCH / 8) + g / NUM_ROWS;
    const int d = g % NUM_ROWS;
    const int n = ring_cnt[d];

    __shared__ unsigned long long skey_s[4][512];  // 16 KB
    __shared__ unsigned short ssrc_s[4][512];      // 4 KB
    unsigned long long* wskey = skey_s[wid];
    unsigned short* wsrc = ssrc_s[wid];

    const int k = gather_ring(b, d, lane, 512, img, mask, prand, out,
                              ring_pix, n, wskey);

    if (k > 512) {
        // deep binomial tail: defer to overflow kernel
        if (lane == 0) {
            const int idx = atomicAdd(ovf_cnt, 1);
            if (idx < OVF_CAP) ovf_list[idx] = b * NUM_ROWS + d;
        }
    } else if (k > 0) {
        asm volatile("s_waitcnt lgkmcnt(0)" ::: "memory");  // wskey visible
        const float* imgb = img + (size_t)b * HW;
        float* outb = out + (size_t)b * HW;
        if (k <= 64)       sort_scatter<0>(wskey, wsrc, k, lane, imgb, outb);
        else if (k <= 128) sort_scatter<1>(wskey, wsrc, k, lane, imgb, outb);
        else if (k <= 256) sort_scatter<2>(wskey, wsrc, k, lane, imgb, outb);
        else               sort_scatter<3>(wskey, wsrc, k, lane, imgb, outb);
    }
}

// Cold path: rings with k > 512 (capacity 1024 >= any ring, rings <= 1024).
__global__ __launch_bounds__(64) void overflow_sort(
    const float* __restrict__ img, const float* __restrict__ mask,
    const float* __restrict__ prand, float* __restrict__ out,
    const int* __restrict__ ring_pix, const int* __restrict__ ring_cnt,
    const int* __restrict__ ovf_cnt, const int* __restrict__ ovf_list) {
    __shared__ unsigned long long wskey[1024];
    __shared__ unsigned short wsrc[1024];
    const int m = min(*ovf_cnt, OVF_CAP);
    const int lane = threadIdx.x;
    for (int t = blockIdx.x; t < m; t += gridDim.x) {
        const int bd = ovf_list[t];
        const int b = bd / NUM_ROWS;
        const int d = bd % NUM_ROWS;
        const int k = gather_ring(b, d, lane, 1024, img, mask, prand, out,
                                  ring_pix, ring_cnt[d], wskey);
        asm volatile("s_waitcnt lgkmcnt(0)" ::: "memory");
        sort_scatter<4>(wskey, wsrc, k, lane,
                        img + (size_t)b * HW, out + (size_t)b * HW);
        __syncthreads();  // before wskey reuse (single wave: cheap)
    }
}

extern "C" void kernel_launch(void* const* d_in, const int* in_sizes, int n_in,
                              void* d_out, int out_size, void* d_ws, size_t ws_size,
                              hipStream_t stream) {
    const float* img   = (const float*)d_in[0];  // (128,224,224,1) f32
    const float* mask  = (const float*)d_in[1];  // (128,224,224)   f32
    const float* prand = (const float*)d_in[2];  // (128,159,1024)  f32
    float* out = (float*)d_out;                  // (128,224,224,1) f32

    int* ring_pix = (int*)d_ws;                       // 159*1024 ints
    int* ring_cnt = ring_pix + NUM_ROWS * NUM_COLS;   // 159 ints
    int* ovf_cnt  = ring_cnt + NUM_ROWS;              // 1 int
    int* ovf_list = ovf_cnt + 1;                      // OVF_CAP ints

    hipLaunchKernelGGL(build_rings, dim3(NUM_ROWS), dim3(256), 0, stream,
                       ring_pix, ring_cnt, ovf_cnt);
    hipLaunchKernelGGL(radial_shuffle, dim3(BATCH * NUM_ROWS / 4), dim3(256), 0,
                       stream, img, mask, prand, out, ring_pix, ring_cnt,
                       ovf_cnt, ovf_list);
    hipLaunchKernelGGL(overflow_sort, dim3(32), dim3(64), 0, stream,
                       img, mask, prand, out, ring_pix, ring_cnt,
                       ovf_cnt, ovf_list);
}